// Round 1
// baseline (217.914 us; speedup 1.0000x reference)
//
#include <hip/hip_runtime.h>
#include <stdint.h>

// CDSSM: conv1(128ch,k3) -> tanh -> conv2(128ch,k3) -> tanh -> max_t -> proj -> tanh
//        then dots(q·pos, q·negs) -> gamma -> softmax.  B=64,T=2048,D=K=K2=128,L=64,J=2.
// Strategy: bf16 MFMA (32x32x16) for both conv layers, fused per-sequence-half blocks.

typedef __bf16 bf16x8 __attribute__((ext_vector_type(8)));
typedef float f32x16 __attribute__((ext_vector_type(16)));
typedef unsigned short u16x8 __attribute__((ext_vector_type(8)));

__device__ __forceinline__ unsigned short f2bf(float f) {
  unsigned u = __builtin_bit_cast(unsigned, f);
  u = u + 0x7FFFu + ((u >> 16) & 1u);   // RTNE
  return (unsigned short)(u >> 16);
}

__device__ __forceinline__ float fast_tanh(float x) {
  x = fminf(10.0f, fmaxf(-10.0f, x));
  float t = __builtin_amdgcn_exp2f(x * -2.8853900817779268f);   // e^{-2x}
  return (1.0f - t) * __builtin_amdgcn_rcpf(1.0f + t);
}

// ---------------- prep: fp32 [k][d][f] -> bf16 [br][f][k][d] ----------------
__global__ void prep_kernel(const float* __restrict__ qw1, const float* __restrict__ qw2,
                            const float* __restrict__ dw1, const float* __restrict__ dw2,
                            unsigned short* __restrict__ W1p, unsigned short* __restrict__ W2p) {
  int gid = blockIdx.x * 256 + threadIdx.x;          // 768*256 = 196608 exact
  int which = gid >= 98304;
  int e = gid - which * 98304;
  int br = e / 49152;
  int r  = e % 49152;
  int f  = r / 16384;
  int r2 = r % 16384;
  int k  = r2 / 128;
  int d  = r2 % 128;
  const float* src = which ? (br ? dw2 : qw2) : (br ? dw1 : qw1);
  float v = src[k * 384 + d * 3 + f];
  (which ? W2p : W1p)[e] = f2bf(v);
}

// ---------------- main fused conv kernel ----------------
// LDS layout (dynamic, 132096 B):
//  W1S_OFF  : bf16 [2 taps][128 k][128 d], row-swizzled   (65536 B)
//  XS_OFF   : bf16 [128 slot][128 d], swizzled            (32768 B)
//  H1S_OFF  : bf16 [128 slot][128 k], swizzled            (32768 B)
//  B1_OFF/B2_OFF : float[128] biases                      (1024 B)
#define W1S_OFF 0
#define XS_OFF  65536
#define H1S_OFF 98304
#define B1_OFF  131072
#define B2_OFF  131584
#define LDS_TOTAL 132096

__global__ __launch_bounds__(512, 2) void cdssm_main(
    const float* __restrict__ q, const float* __restrict__ pos, const float* __restrict__ negs,
    const unsigned short* __restrict__ W1p, const unsigned short* __restrict__ W2p,
    const float* __restrict__ qb1, const float* __restrict__ qb2,
    const float* __restrict__ db1, const float* __restrict__ db2,
    float* __restrict__ hpart) {
  extern __shared__ char lds[];
  const int tid = threadIdx.x;
  const int bid = blockIdx.x;
  const int seq = bid >> 1;
  const int half = bid & 1;
  const int branch = (seq < 64) ? 0 : 1;
  const float* xptr = (seq < 64) ? (q + (size_t)seq * 2048 * 128)
                    : (seq < 128) ? (pos + (size_t)(seq - 64) * 2048 * 128)
                                  : (negs + (size_t)(seq - 128) * 2048 * 128);
  const float* b1g = branch ? db1 : qb1;
  const float* b2g = branch ? db2 : qb2;
  const int lo = half * 1022;
  const int hi = lo + 1022;   // both halves: 1022 outputs, total 2044

  // ---- stage W1 taps 0,1 into LDS (swizzled) + biases ----
  {
    const unsigned short* w1src = W1p + (size_t)branch * 49152;
    for (int ch = tid; ch < 4096; ch += 512) {       // 65536B / 16B
      int e = ch * 8;
      int f = e >> 14;
      int krow = (e >> 7) & 127;
      int d0 = e & 127;
      u16x8 v = *(const u16x8*)(w1src + ((f * 128 + krow) * 128 + d0));
      *(u16x8*)(lds + W1S_OFF + (f * 128 + krow) * 256 + ((d0 * 2) ^ ((krow & 15) << 4))) = v;
    }
    if (tid < 128) ((float*)(lds + B1_OFF))[tid] = b1g[tid];
    else if (tid < 256) ((float*)(lds + B2_OFF))[tid - 128] = b2g[tid - 128];
  }

  const int lane = tid & 63;
  const int w = tid >> 6;            // 8 waves
  const int lrow = lane & 31;
  const int hi5 = lane >> 5;         // k-group
  const int r0 = (w & 3) * 32;       // output-row tile
  const int cbase = (w >> 2) * 64;   // 2 col tiles of 32
  const int row1 = r0 + lrow;

  // register fragments: W1 tap2 (this wave's rows), all of W2 (this wave's rows)
  bf16x8 a1t2[8], a2s[24];
  {
    const unsigned short* w1src = W1p + (size_t)branch * 49152;
    const unsigned short* w2src = W2p + (size_t)branch * 49152;
#pragma unroll
    for (int kk = 0; kk < 8; ++kk)
      a1t2[kk] = __builtin_bit_cast(bf16x8,
          *(const u16x8*)(w1src + ((2 * 128 + row1) * 128 + kk * 16 + hi5 * 8)));
#pragma unroll
    for (int f = 0; f < 3; ++f)
#pragma unroll
      for (int kk = 0; kk < 8; ++kk)
        a2s[f * 8 + kk] = __builtin_bit_cast(bf16x8,
            *(const u16x8*)(w2src + ((f * 128 + row1) * 128 + kk * 16 + hi5 * 8)));
  }

  // B-operand LDS address bases per (col-tile, tap)
  int bbase[2][3], bswz[2][3];
#pragma unroll
  for (int cf = 0; cf < 2; ++cf)
#pragma unroll
    for (int f = 0; f < 3; ++f) {
      int c = cbase + cf * 32 + lrow;
      int slot = min(c + f, 127);
      bbase[cf][f] = XS_OFF + slot * 256;
      bswz[cf][f] = (slot & 15) << 4;
    }
  const int arow = row1 * 256;                 // + W1S_OFF + f*32768
  const int aswz = (lrow & 15) << 4;
  const int hi16 = hi5 * 16;                   // byte offset of k-group

  float vmax[16];
#pragma unroll
  for (int r = 0; r < 16; ++r) vmax[r] = -2.0f;

  for (int it = 0; it < 9; ++it) {
    const int a = lo + it * 126;
    __syncthreads();   // (A) staging / previous iter complete
    if (it > 0 && tid < 64) {   // halo: slots 126,127 -> 0,1 for Xs and h1s (re-swizzled)
      int buf = (tid >> 5) & 1;
      int sl = (tid >> 4) & 1;
      int o = (tid & 15) * 16;
      int off = buf ? H1S_OFF : XS_OFF;
      u16x8 v = *(const u16x8*)(lds + off + (126 + sl) * 256 + (o ^ (((126 + sl) & 15) << 4)));
      *(u16x8*)(lds + off + sl * 256 + (o ^ ((sl & 15) << 4))) = v;
    }
    __syncthreads();   // (B) halo done
    {                  // fresh X -> bf16 -> LDS
      int s0 = (it == 0) ? 0 : 2;
      int nch = (128 - s0) * 16;
      for (int ch = tid; ch < nch; ch += 512) {
        int slot = s0 + (ch >> 4);
        int d0 = (ch & 15) * 8;
        int t = a + slot; if (t > 2047) t = 2047;   // clamped reads only feed masked outputs
        const float* src = xptr + ((size_t)t * 128 + d0);
        float4 v0 = *(const float4*)src;
        float4 v1 = *(const float4*)(src + 4);
        u16x8 u;
        u[0] = f2bf(v0.x); u[1] = f2bf(v0.y); u[2] = f2bf(v0.z); u[3] = f2bf(v0.w);
        u[4] = f2bf(v1.x); u[5] = f2bf(v1.y); u[6] = f2bf(v1.z); u[7] = f2bf(v1.w);
        *(u16x8*)(lds + XS_OFF + slot * 256 + ((d0 * 2) ^ ((slot & 15) << 4))) = u;
      }
    }
    __syncthreads();   // (C) X ready

    // ---- layer 1: h1[k, c] = tanh(b1 + sum_f sum_d W1[k,d,f] * X[a+c+f, d]) ----
    {
      f32x16 acc0, acc1;
#pragma unroll
      for (int r = 0; r < 16; ++r) { acc0[r] = 0.f; acc1[r] = 0.f; }
#pragma unroll
      for (int f = 0; f < 2; ++f)
#pragma unroll
        for (int kk = 0; kk < 8; ++kk) {
          bf16x8 af = __builtin_bit_cast(bf16x8,
              *(const u16x8*)(lds + W1S_OFF + f * 32768 + arow + ((kk * 32 + hi16) ^ aswz)));
          bf16x8 b0 = __builtin_bit_cast(bf16x8,
              *(const u16x8*)(lds + bbase[0][f] + ((kk * 32 + hi16) ^ bswz[0][f])));
          acc0 = __builtin_amdgcn_mfma_f32_32x32x16_bf16(af, b0, acc0, 0, 0, 0);
          bf16x8 b1v = __builtin_bit_cast(bf16x8,
              *(const u16x8*)(lds + bbase[1][f] + ((kk * 32 + hi16) ^ bswz[1][f])));
          acc1 = __builtin_amdgcn_mfma_f32_32x32x16_bf16(af, b1v, acc1, 0, 0, 0);
        }
#pragma unroll
      for (int kk = 0; kk < 8; ++kk) {
        bf16x8 b0 = __builtin_bit_cast(bf16x8,
            *(const u16x8*)(lds + bbase[0][2] + ((kk * 32 + hi16) ^ bswz[0][2])));
        acc0 = __builtin_amdgcn_mfma_f32_32x32x16_bf16(a1t2[kk], b0, acc0, 0, 0, 0);
        bf16x8 b1v = __builtin_bit_cast(bf16x8,
            *(const u16x8*)(lds + bbase[1][2] + ((kk * 32 + hi16) ^ bswz[1][2])));
        acc1 = __builtin_amdgcn_mfma_f32_32x32x16_bf16(a1t2[kk], b1v, acc1, 0, 0, 0);
      }
#pragma unroll
      for (int cf = 0; cf < 2; ++cf) {
        const f32x16 acc = cf ? acc1 : acc0;
        int c = cbase + cf * 32 + lrow;      // C layout: col = lane&31
        if (c < 126) {
          int slot = c + 2;
          int wb = H1S_OFF + slot * 256;
          int wz = (slot & 15) << 4;
#pragma unroll
          for (int qd = 0; qd < 4; ++qd) {
            int k0 = r0 + qd * 8 + hi5 * 4;  // C rows: (reg&3)+8*(reg>>2)+4*hi
            float4 bq = *(const float4*)(lds + B1_OFF + k0 * 4);
            unsigned short h0 = f2bf(fast_tanh(acc[qd * 4 + 0] + bq.x));
            unsigned short h1v = f2bf(fast_tanh(acc[qd * 4 + 1] + bq.y));
            unsigned short h2 = f2bf(fast_tanh(acc[qd * 4 + 2] + bq.z));
            unsigned short h3 = f2bf(fast_tanh(acc[qd * 4 + 3] + bq.w));
            uint2 pk;
            pk.x = (unsigned)h0 | ((unsigned)h1v << 16);
            pk.y = (unsigned)h2 | ((unsigned)h3 << 16);
            *(uint2*)(lds + wb + ((k0 * 2) ^ wz)) = pk;
          }
        }
      }
    }
    __syncthreads();   // (D) h1 ready

    // ---- layer 2: y2[k2, t2] = tanh(b2 + sum_f sum_c W2[k2,c,f] * h1[c, t2+f]), t2 = a-2+c2 ----
    {
      f32x16 acc0, acc1;
#pragma unroll
      for (int r = 0; r < 16; ++r) { acc0[r] = 0.f; acc1[r] = 0.f; }
#pragma unroll
      for (int f = 0; f < 3; ++f)
#pragma unroll
        for (int kk = 0; kk < 8; ++kk) {
          bf16x8 b0 = __builtin_bit_cast(bf16x8,
              *(const u16x8*)(lds + bbase[0][f] + 32768 + ((kk * 32 + hi16) ^ bswz[0][f])));
          acc0 = __builtin_amdgcn_mfma_f32_32x32x16_bf16(a2s[f * 8 + kk], b0, acc0, 0, 0, 0);
          bf16x8 b1v = __builtin_bit_cast(bf16x8,
              *(const u16x8*)(lds + bbase[1][f] + 32768 + ((kk * 32 + hi16) ^ bswz[1][f])));
          acc1 = __builtin_amdgcn_mfma_f32_32x32x16_bf16(a2s[f * 8 + kk], b1v, acc1, 0, 0, 0);
        }
#pragma unroll
      for (int cf = 0; cf < 2; ++cf) {
        const f32x16 acc = cf ? acc1 : acc0;
        int c2 = cbase + cf * 32 + lrow;
        int t2 = a - 2 + c2;
        bool valid = (c2 < 126) && (t2 >= lo) && (t2 < hi);
#pragma unroll
        for (int qd = 0; qd < 4; ++qd) {
          int k0 = r0 + qd * 8 + hi5 * 4;
          float4 bq = *(const float4*)(lds + B2_OFF + k0 * 4);
#pragma unroll
          for (int jj = 0; jj < 4; ++jj) {
            float v = fast_tanh(acc[qd * 4 + jj] + ((const float*)&bq)[jj]);
            v = valid ? v : -2.0f;
            vmax[qd * 4 + jj] = fmaxf(vmax[qd * 4 + jj], v);
          }
        }
      }
    }
  }

  __syncthreads();
  // reduce vmax across the 32 columns (each half-wave holds its own 16 rows)
#pragma unroll
  for (int r = 0; r < 16; ++r) {
    float v = vmax[r];
    v = fmaxf(v, __shfl_xor(v, 1, 64));
    v = fmaxf(v, __shfl_xor(v, 2, 64));
    v = fmaxf(v, __shfl_xor(v, 4, 64));
    v = fmaxf(v, __shfl_xor(v, 8, 64));
    v = fmaxf(v, __shfl_xor(v, 16, 64));
    vmax[r] = v;
  }
  float* hbuf = (float*)(lds + XS_OFF);   // reuse Xs region
  if (w < 4 && lrow == 0) {
#pragma unroll
    for (int r = 0; r < 16; ++r)
      hbuf[r0 + (r & 3) + 8 * (r >> 2) + 4 * hi5] = vmax[r];
  }
  __syncthreads();
  if (w >= 4 && lrow == 0) {
#pragma unroll
    for (int r = 0; r < 16; ++r) {
      int row = r0 + (r & 3) + 8 * (r >> 2) + 4 * hi5;
      hbuf[row] = fmaxf(hbuf[row], vmax[r]);
    }
  }
  __syncthreads();
  if (tid < 128) hpart[(size_t)bid * 128 + tid] = hbuf[tid];
}

// ---------------- k2: combine halves, project, tanh ----------------
__global__ void k2_proj(const float* __restrict__ hpart,
                        const float* __restrict__ qsw, const float* __restrict__ qsb,
                        const float* __restrict__ dsw, const float* __restrict__ dsb,
                        float* __restrict__ s_out) {
  int seq = blockIdx.x;        // 256
  int l = threadIdx.x;         // 64
  const float* sw = (seq < 64) ? qsw : dsw;
  const float* sb = (seq < 64) ? qsb : dsb;
  const float* h0 = hpart + (size_t)(2 * seq) * 128;
  const float* h1 = h0 + 128;
  float acc = sb[l];
  for (int k = 0; k < 128; ++k)
    acc += fmaxf(h0[k], h1[k]) * sw[l * 128 + k];
  s_out[(size_t)seq * 64 + l] = fast_tanh(acc);
}

// ---------------- k3: dots, gamma, softmax ----------------
__global__ void k3_softmax(const float* __restrict__ s_out,
                           const float* __restrict__ gw, const float* __restrict__ gb,
                           float* __restrict__ out) {
  int b = threadIdx.x;   // 64
  const float* qs = s_out + (size_t)b * 64;
  const float* ps = s_out + (size_t)(64 + b) * 64;
  const float* n0 = s_out + (size_t)(128 + b) * 64;
  const float* n1 = s_out + (size_t)(192 + b) * 64;
  float d0 = 0.f, d1 = 0.f, d2 = 0.f;
  for (int l = 0; l < 64; ++l) {
    float v = qs[l];
    d0 += v * ps[l];
    d1 += v * n0[l];
    d2 += v * n1[l];
  }
  float g = gw[0], bb = gb[0];
  d0 = g * d0 + bb; d1 = g * d1 + bb; d2 = g * d2 + bb;
  float m = fmaxf(d0, fmaxf(d1, d2));
  float e0 = expf(d0 - m), e1 = expf(d1 - m), e2 = expf(d2 - m);
  float inv = 1.0f / (e0 + e1 + e2);
  out[b * 3 + 0] = e0 * inv;
  out[b * 3 + 1] = e1 * inv;
  out[b * 3 + 2] = e2 * inv;
}

extern "C" void kernel_launch(void* const* d_in, const int* in_sizes, int n_in,
                              void* d_out, int out_size, void* d_ws, size_t ws_size,
                              hipStream_t stream) {
  const float* q    = (const float*)d_in[0];
  const float* pos  = (const float*)d_in[1];
  const float* negs = (const float*)d_in[2];
  const float* qw1  = (const float*)d_in[3];
  const float* qb1  = (const float*)d_in[4];
  const float* qw2  = (const float*)d_in[5];
  const float* qb2  = (const float*)d_in[6];
  const float* qsw  = (const float*)d_in[7];
  const float* qsb  = (const float*)d_in[8];
  const float* dw1  = (const float*)d_in[9];
  const float* db1  = (const float*)d_in[10];
  const float* dw2  = (const float*)d_in[11];
  const float* db2  = (const float*)d_in[12];
  const float* dsw  = (const float*)d_in[13];
  const float* dsb  = (const float*)d_in[14];
  const float* gw   = (const float*)d_in[15];
  const float* gb   = (const float*)d_in[16];
  float* out = (float*)d_out;

  char* ws = (char*)d_ws;
  unsigned short* W1p = (unsigned short*)(ws);             // 2*3*128*128 bf16 = 196608 B
  unsigned short* W2p = (unsigned short*)(ws + 196608);    // 196608 B
  float* hpart        = (float*)(ws + 393216);             // 512*128*4 = 262144 B
  float* s_out        = (float*)(ws + 655360);             // 256*64*4  = 65536 B

  hipFuncSetAttribute((const void*)cdssm_main,
                      hipFuncAttributeMaxDynamicSharedMemorySize, LDS_TOTAL);

  prep_kernel<<<768, 256, 0, stream>>>(qw1, qw2, dw1, dw2, W1p, W2p);
  cdssm_main<<<512, 512, LDS_TOTAL, stream>>>(q, pos, negs, W1p, W2p, qb1, qb2, db1, db2, hpart);
  k2_proj<<<256, 64, 0, stream>>>(hpart, qsw, qsb, dsw, dsb, s_out);
  k3_softmax<<<1, 64, 0, stream>>>(s_out, gw, gb, out);
}